// Round 7
// baseline (547.481 us; speedup 1.0000x reference)
//
#include <hip/hip_runtime.h>
#include <hip/hip_bf16.h>
#include <cmath>

// Problem constants
#define Bq   4
#define Lq   4096
#define Wq   2048
#define Hq   8
#define Mq   (Bq*Lq)        // 16384 rows
#define RCH  128            // rows per chunk in scan (8 waves x 16 rows)
#define NCH  (Lq/RCH)       // 32 chunks per sequence

typedef __bf16 bf16;
typedef __attribute__((ext_vector_type(8))) __bf16 bf16x8;
typedef __attribute__((ext_vector_type(4))) float  f32x4;

// ---- workspace layout (bytes) ----
#define WS_WT    0                               // bf16 [2][8][256][256] = 2 MiB (n-major)
#define WS_C     (2*8*256*256*2)                 // float [2048]
#define WS_PH    (4u<<20)                        // u32 [Mq*Wq]: packed (xn bf16 | a u16) = 134 MiB

// ---------------- K0: weight transpose/cast (LDS tiled) + c vector ----------------
__global__ __launch_bounds__(256) void prep2(const float* __restrict__ ig_w,
                                             const float* __restrict__ ag_w,
                                             const float* __restrict__ a_param,
                                             bf16* __restrict__ wt, float* __restrict__ c_arr) {
    __shared__ float t[64*65];
    int bid = blockIdx.x;                 // 256 blocks: [g:1][h:3][nt:2][kt:2]
    int kt = bid & 3, nt = (bid >> 2) & 3, h = (bid >> 4) & 7, g = bid >> 7;
    const float* src = g ? ag_w : ig_w;
    int rr = threadIdx.x >> 6, cc = threadIdx.x & 63;
#pragma unroll
    for (int p = 0; p < 16; p++) {
        int kl = p*4 + rr;
        t[kl*65 + cc] = src[h*65536 + (kt*64 + kl)*256 + nt*64 + cc];  // coalesced read
    }
    if (bid < 8) {
        float ap = a_param[bid*256 + threadIdx.x];
        c_arr[bid*256 + threadIdx.x] = 8.0f * log1pf(__expf(ap));      // 8*softplus
    }
    __syncthreads();
#pragma unroll
    for (int p = 0; p < 16; p++) {
        int nl = p*4 + rr;
        wt[((size_t)((g*8 + h)*256) + nt*64 + nl)*256 + kt*64 + cc] = (bf16)t[cc*65 + nl]; // coalesced write
    }
}

// ---------------- K1: streaming GEMM + gates -> packed (xn bf16 | a u16) -----------
// 512 blocks = (h:8, s:8 stripes of 32 cols, mq:8 row-eighths), bid = (h*8+s)*8+mq.
// bid%8 == mq: the 8 stripe-siblings of an (h, mq) x-region share an XCD's L2.
// 2 blocks/CU, 4 waves/SIMD, NO in-loop barriers, no serial chain: pure streaming.
// Each block: weights for its 32-col stripe (both gates) resident in 32 KB LDS in
// exact MFMA B-fragment order; streams 2048 rows in 16 iters of 128 rows.
// Packing: a -> u16 fixed-point (abs err 1.5e-5: a-errors COMPOUND over the scan
// window ~1/(1-a), bf16's 2e-3 would not pass); xn -> bf16 RTNE (one-shot error).
__global__ __launch_bounds__(512, 4) void gates_pack(
    const float* __restrict__ x, const int* __restrict__ segpos,
    const bf16* __restrict__ wt, const float* __restrict__ igb,
    const float* __restrict__ agb, const float* __restrict__ c_arr,
    unsigned* __restrict__ PH)
{
    __shared__ bf16x8 Wl[32*64];                 // [(g*2+ct)*8+ks][lane] frags, 32 KB

    const int tid = threadIdx.x;
    const int bid = blockIdx.x;
    const int h = bid >> 6, s = (bid >> 3) & 7, mq = bid & 7;
    const int lane = tid & 63, wv = tid >> 6;
    const int l16 = lane & 15, quad = lane >> 4;
    const int wcol0 = h*256 + s*32;

    // ---- weight LDS fill in exact B-fragment order (one-time, 32 KB)
    for (int t = tid; t < 2048; t += 512) {
        int ln = t & 63, ks = (t >> 6) & 7, ct = (t >> 9) & 1, g = t >> 10;
        int n  = s*32 + ct*16 + (ln & 15);
        int k  = ks*32 + (ln >> 4)*8;
        Wl[t] = *(const bf16x8*)&wt[((size_t)((g*8 + h)*256 + n))*256 + k];
    }
    float bxv[2], bav[2], ccv[2];
#pragma unroll
    for (int ct = 0; ct < 2; ct++) {
        int wf = wcol0 + ct*16 + l16;
        bxv[ct] = igb[wf]; bav[ct] = agb[wf]; ccv[ct] = c_arr[wf];
    }
    __syncthreads();

    const int mb0 = mq*2048;
#pragma unroll 1
    for (int it = 0; it < 16; ++it) {
        const int mb = mb0 + it*128;
        // fragment-layout loads: lane (l16,quad) -> row mb+wv*16+l16, cols quad*8 (+ks*32)
        const float* xf = x + ((size_t)(mb + wv*16 + l16))*Wq + h*256 + quad*8;
        float4 u0[8], u1[8];
#pragma unroll
        for (int ks = 0; ks < 8; ks++) {
            u0[ks] = *(const float4*)(xf + ks*32);
            u1[ks] = *(const float4*)(xf + ks*32 + 4);
        }
        f32x4 ax[2], aa[2];
#pragma unroll
        for (int j = 0; j < 2; j++) { ax[j] = (f32x4){0.f,0.f,0.f,0.f}; aa[j] = (f32x4){0.f,0.f,0.f,0.f}; }
#pragma unroll
        for (int ks = 0; ks < 8; ks++) {
            bf16x8 af;
            af[0]=(bf16)u0[ks].x; af[1]=(bf16)u0[ks].y; af[2]=(bf16)u0[ks].z; af[3]=(bf16)u0[ks].w;
            af[4]=(bf16)u1[ks].x; af[5]=(bf16)u1[ks].y; af[6]=(bf16)u1[ks].z; af[7]=(bf16)u1[ks].w;
            bf16x8 w0 = Wl[(0*8+ks)*64 + lane];   // ig, ct=0
            bf16x8 w1 = Wl[(1*8+ks)*64 + lane];   // ig, ct=1
            bf16x8 w2 = Wl[(2*8+ks)*64 + lane];   // ag, ct=0
            bf16x8 w3 = Wl[(3*8+ks)*64 + lane];   // ag, ct=1
            ax[0] = __builtin_amdgcn_mfma_f32_16x16x32_bf16(af, w0, ax[0], 0,0,0);
            ax[1] = __builtin_amdgcn_mfma_f32_16x16x32_bf16(af, w1, ax[1], 0,0,0);
            aa[0] = __builtin_amdgcn_mfma_f32_16x16x32_bf16(af, w2, aa[0], 0,0,0);
            aa[1] = __builtin_amdgcn_mfma_f32_16x16x32_bf16(af, w3, aa[1], 0,0,0);
        }

        // gate-layout epilogue: lane (quad,l16) -> rows mb+wv*16+quad*4+r, col wcol0+ct*16+l16
        const int grow = mb + wv*16 + quad*4;
        const float* xg = x + (size_t)grow*Wq + wcol0 + l16;
        int4 sp = *(const int4*)(segpos + (grow & (Lq-1)));
        int spv[4]; spv[0]=sp.x; spv[1]=sp.y; spv[2]=sp.z; spv[3]=sp.w;
        unsigned* pp = PH + (size_t)grow*Wq + wcol0 + l16;
#pragma unroll
        for (int r = 0; r < 4; r++) {
            bool rst = (spv[r] == 0);
#pragma unroll
            for (int ct = 0; ct < 2; ct++) {
                float zx = ax[ct][r] + bxv[ct];
                float za = aa[ct][r] + bav[ct];
                float gx = __builtin_amdgcn_rcpf(1.f + __expf(-zx));
                float ga = __builtin_amdgcn_rcpf(1.f + __expf(-za));
                float a  = __expf(-ga * ccv[ct]);
                float mult = __builtin_amdgcn_sqrtf(fmaf(-a, a, 1.f)); // sqrt(1-a^2)
                if (rst) { a = 0.f; mult = 1.f; }
                float xn = gx * mult * xg[(size_t)r*Wq + ct*16];
                unsigned xb = __float_as_uint(xn);
                xb = (xb + 0x7FFFu + ((xb >> 16) & 1u)) & 0xFFFF0000u;   // RTNE to bf16 bits
                unsigned au = (unsigned)fmaf(a, 65535.f, 0.5f);          // a in [0,1) -> u16
                pp[(size_t)r*Wq + ct*16] = xb | au;
            }
        }
    }
}

// ---------------- K2: segmented scan over packed (a, xn) -> y, last_h --------------
// 256 blocks = (s:8)*(b:4)*(h:8); block owns 32 channels of one batch, walks 32
// chunks of 128 rows. Round-4's verified scan machinery: in-lane 4-row scan,
// 2-step Kogge-Stone over quads (__shfl), cross-wave ladder with parity
// ping-ponged sg/hc and ONE barrier per chunk (hazard audit as round 4).
__global__ __launch_bounds__(512, 4) void scan_apply(
    const unsigned* __restrict__ PH, const float* __restrict__ prev_h,
    float* __restrict__ out)
{
    __shared__ float sgA[2][8][32], sgH[2][8][32];
    __shared__ float hc[2][32];

    const int tid = threadIdx.x;
    const int bid = blockIdx.x;
    const int h = bid & 7, b = (bid >> 3) & 3, s = bid >> 5;
    const int lane = tid & 63, wv = tid >> 6;
    const int l16 = lane & 15, quad = lane >> 4;
    const int wcol0 = h*256 + s*32;

    if (tid < 32) hc[0][tid] = prev_h[b*Wq + wcol0 + tid];
    __syncthreads();

    for (int c = 0; c < NCH; ++c) {
        const int cur = c & 1, nxt = cur ^ 1;
        const int grow = b*Lq + c*RCH + wv*16 + quad*4;   // global row of r=0
        const unsigned* pp = PH + (size_t)grow*Wq + wcol0 + l16;

        float av[8], xn[8];
#pragma unroll
        for (int r = 0; r < 4; r++)
#pragma unroll
            for (int ct = 0; ct < 2; ct++) {
                unsigned pk = pp[(size_t)r*Wq + ct*16];
                xn[r*2+ct] = __uint_as_float(pk & 0xFFFF0000u);
                av[r*2+ct] = (float)(pk & 0xFFFFu) * (1.0f/65535.0f);
            }

        // ---- phase B: in-lane scan + Kogge-Stone over quads
        float Pl[8], hl[8], Awv[2], Hwv[2];
#pragma unroll
        for (int ct = 0; ct < 2; ct++) {
            float A = 1.f, hv = 0.f;
#pragma unroll
            for (int r = 0; r < 4; r++) {
                hv = fmaf(av[r*2+ct], hv, xn[r*2+ct]);
                A *= av[r*2+ct];
                Pl[ct*4+r] = A; hl[ct*4+r] = hv;
            }
            float Asc = A, Hsc = hv;
            float Apv = __shfl(Asc, (lane-16) & 63), Hpv = __shfl(Hsc, (lane-16) & 63);
            if (quad >= 1) { Hsc = fmaf(Asc, Hpv, Hsc); Asc *= Apv; }
            Apv = __shfl(Asc, (lane-32) & 63); Hpv = __shfl(Hsc, (lane-32) & 63);
            if (quad >= 2) { Hsc = fmaf(Asc, Hpv, Hsc); Asc *= Apv; }
            float Aex = __shfl(Asc, (lane-16) & 63), Hex = __shfl(Hsc, (lane-16) & 63); // exclusive
            if (quad == 0) { Aex = 1.f; Hex = 0.f; }
#pragma unroll
            for (int r = 0; r < 4; r++) {
                hl[ct*4+r] = fmaf(Pl[ct*4+r], Hex, hl[ct*4+r]);
                Pl[ct*4+r] *= Aex;
            }
            Awv[ct] = Asc; Hwv[ct] = Hsc;
            if (quad == 3) { sgA[cur][wv][ct*16+l16] = Asc; sgH[cur][wv][ct*16+l16] = Hsc; }
        }
        __syncthreads();

        // ---- phase C: cross-wave ladder + store y + carry
#pragma unroll
        for (int ct = 0; ct < 2; ct++) {
            int col = ct*16 + l16;
            float h0 = hc[cur][col];
#pragma unroll
            for (int w = 0; w < 7; w++)
                if (w < wv) h0 = fmaf(sgA[cur][w][col], h0, sgH[cur][w][col]);
            float* yp = out + (size_t)grow*Wq + wcol0 + col;
#pragma unroll
            for (int r = 0; r < 4; r++)
                yp[(size_t)r*Wq] = fmaf(Pl[ct*4+r], h0, hl[ct*4+r]);
            if (wv == 7 && quad == 3)
                hc[nxt][col] = fmaf(Awv[ct], h0, Hwv[ct]);
        }
    }
    __syncthreads();
    if (tid < 32) out[(size_t)Mq*Wq + b*Wq + wcol0 + tid] = hc[NCH & 1][tid];  // last_h
}

extern "C" void kernel_launch(void* const* d_in, const int* in_sizes, int n_in,
                              void* d_out, int out_size, void* d_ws, size_t ws_size,
                              hipStream_t stream) {
    const float* x       = (const float*)d_in[0];
    const int*   segpos  = (const int*)  d_in[1];
    const float* prev_h  = (const float*)d_in[2];
    const float* ig_w    = (const float*)d_in[3];
    const float* ig_b    = (const float*)d_in[4];
    const float* ag_w    = (const float*)d_in[5];
    const float* ag_b    = (const float*)d_in[6];
    const float* a_param = (const float*)d_in[7];
    float* out = (float*)d_out;                    // [M*W] y then [B*W] last_h

    char* ws = (char*)d_ws;
    bf16*     wt    = (bf16*)    (ws + WS_WT);
    float*    c_arr = (float*)   (ws + WS_C);
    unsigned* PH    = (unsigned*)(ws + WS_PH);

    prep2<<<256, 256, 0, stream>>>(ig_w, ag_w, a_param, wt, c_arr);
    gates_pack<<<512, 512, 0, stream>>>(x, segpos, wt, ig_b, ag_b, c_arr, PH);
    scan_apply<<<256, 512, 0, stream>>>(PH, prev_h, out);
}